// Round 1
// baseline (5304.033 us; speedup 1.0000x reference)
//
#include <hip/hip_runtime.h>
#include <math.h>

#define NS 512
#define NE 2048
#define NB 64
#define NT 512

// out[c][r] = in[r][c]; rows, cols multiples of 32
__global__ __launch_bounds__(256) void transpose_k(const float* __restrict__ in,
                                                   float* __restrict__ out,
                                                   int rows, int cols) {
  __shared__ float tile[32][33];
  int c0 = blockIdx.x * 32;
  int r0 = blockIdx.y * 32;
  int tx = threadIdx.x;  // 0..31
  int ty = threadIdx.y;  // 0..7
#pragma unroll
  for (int k = 0; k < 32; k += 8) {
    tile[ty + k][tx] = in[(size_t)(r0 + ty + k) * cols + (c0 + tx)];
  }
  __syncthreads();
#pragma unroll
  for (int k = 0; k < 32; k += 8) {
    out[(size_t)(c0 + ty + k) * rows + (r0 + tx)] = tile[tx][ty + k];
  }
}

// Forward: one block per batch, thread j owns state j. Stores v[t][b][:] for all t.
__global__ __launch_bounds__(512) void viterbi_fwd(
    const int* __restrict__ obs,     // [NB][NT]
    const float* __restrict__ start, // [NS]
    const float* __restrict__ trans, // [NS][NS]
    const float* __restrict__ emT,   // [NE][NS]
    float* __restrict__ v)           // [NT][NB][NS]
{
  const int b = blockIdx.x;
  const int j = threadIdx.x;
  __shared__ __align__(16) float vcur[NS];

  // t = 0
  float vj = start[j] + emT[(size_t)obs[b * NT] * NS + j];
  vcur[j] = vj;
  v[((size_t)0 * NB + b) * NS + j] = vj;
  __syncthreads();

  for (int t = 1; t < NT; ++t) {
    float m0 = -INFINITY, m1 = -INFINITY, m2 = -INFINITY, m3 = -INFINITY;
    const float* tj = trans + j;
#pragma unroll 4
    for (int i = 0; i < NS; i += 8) {
      float4 va = *reinterpret_cast<const float4*>(vcur + i);
      float4 vb = *reinterpret_cast<const float4*>(vcur + i + 4);
      float s0 = va.x + tj[(size_t)(i + 0) * NS];
      float s1 = va.y + tj[(size_t)(i + 1) * NS];
      float s2 = va.z + tj[(size_t)(i + 2) * NS];
      float s3 = va.w + tj[(size_t)(i + 3) * NS];
      float s4 = vb.x + tj[(size_t)(i + 4) * NS];
      float s5 = vb.y + tj[(size_t)(i + 5) * NS];
      float s6 = vb.z + tj[(size_t)(i + 6) * NS];
      float s7 = vb.w + tj[(size_t)(i + 7) * NS];
      m0 = fmaxf(m0, fmaxf(s0, s1));  // -> v_max3
      m1 = fmaxf(m1, fmaxf(s2, s3));
      m2 = fmaxf(m2, fmaxf(s4, s5));
      m3 = fmaxf(m3, fmaxf(s6, s7));
    }
    float m = fmaxf(fmaxf(m0, m1), fmaxf(m2, m3));
    float e = emT[(size_t)obs[b * NT + t] * NS + j];
    float vn = m + e;
    __syncthreads();  // all reads of vcur for this step done
    vcur[j] = vn;
    v[((size_t)t * NB + b) * NS + j] = vn;
    __syncthreads();
  }
}

// Backtrace: one wave per batch; recompute argmax with exact first-wins ties.
__global__ __launch_bounds__(64) void viterbi_bt(
    const float* __restrict__ v,      // [NT][NB][NS]
    const float* __restrict__ transT, // [NS][NS], transT[j][i] = trans[i][j]
    int* __restrict__ path)           // [NB][NT] int32
{
  const int b = blockIdx.x;
  const int lane = threadIdx.x;

  // argmax over final v row (first index wins)
  float val = -INFINITY;
  int idx = 0;
  const float* vrow = v + ((size_t)(NT - 1) * NB + b) * NS;
#pragma unroll
  for (int k = 0; k < NS; k += 64) {
    float s = vrow[k + lane];
    if (s > val) { val = s; idx = k + lane; }  // ascending k => strict > keeps first
  }
#pragma unroll
  for (int off = 32; off; off >>= 1) {
    float v2 = __shfl_down(val, off);
    int i2 = __shfl_down(idx, off);
    if (v2 > val || (v2 == val && i2 < idx)) { val = v2; idx = i2; }
  }
  int state = __shfl(idx, 0);
  if (lane == 0) path[b * NT + (NT - 1)] = state;

  for (int t = NT - 1; t >= 1; --t) {
    const float* vp = v + ((size_t)(t - 1) * NB + b) * NS;
    const float* tr = transT + (size_t)state * NS;
    float val2 = -INFINITY;
    int idx2 = 0;
#pragma unroll
    for (int k = 0; k < NS; k += 64) {
      float s = vp[k + lane] + tr[k + lane];
      if (s > val2) { val2 = s; idx2 = k + lane; }
    }
#pragma unroll
    for (int off = 32; off; off >>= 1) {
      float v2 = __shfl_down(val2, off);
      int i2 = __shfl_down(idx2, off);
      if (v2 > val2 || (v2 == val2 && i2 < idx2)) { val2 = v2; idx2 = i2; }
    }
    state = __shfl(idx2, 0);
    if (lane == 0) path[b * NT + (t - 1)] = state;
  }
}

extern "C" void kernel_launch(void* const* d_in, const int* in_sizes, int n_in,
                              void* d_out, int out_size, void* d_ws, size_t ws_size,
                              hipStream_t stream) {
  const int* obs = (const int*)d_in[0];       // [64][512]
  const float* start = (const float*)d_in[1]; // [512]
  const float* trans = (const float*)d_in[2]; // [512][512]
  const float* emis = (const float*)d_in[3];  // [512][2048]
  int* path = (int*)d_out;                    // [64][512] int32

  char* ws = (char*)d_ws;
  float* emT = (float*)ws;                          // [2048][512] = 4 MB
  float* transT = (float*)(ws + (4u << 20));        // [512][512]  = 1 MB
  float* v = (float*)(ws + (5u << 20));             // [512][64][512] = 64 MB

  dim3 tb(32, 8);
  transpose_k<<<dim3(NE / 32, NS / 32), tb, 0, stream>>>(emis, emT, NS, NE);
  transpose_k<<<dim3(NS / 32, NS / 32), tb, 0, stream>>>(trans, transT, NS, NS);
  viterbi_fwd<<<NB, NS, 0, stream>>>(obs, start, trans, emT, v);
  viterbi_bt<<<NB, 64, 0, stream>>>(v, transT, path);
}

// Round 2
// 4677.239 us; speedup vs baseline: 1.1340x; 1.1340x over previous
//
#include <hip/hip_runtime.h>
#include <math.h>

#define NS 512
#define NE 2048
#define NB 64
#define NT 512

// out[c][r] = in[r][c]; rows, cols multiples of 32
__global__ __launch_bounds__(256) void transpose_k(const float* __restrict__ in,
                                                   float* __restrict__ out,
                                                   int rows, int cols) {
  __shared__ float tile[32][33];
  int c0 = blockIdx.x * 32;
  int r0 = blockIdx.y * 32;
  int tx = threadIdx.x;  // 0..31
  int ty = threadIdx.y;  // 0..7
#pragma unroll
  for (int k = 0; k < 32; k += 8) {
    tile[ty + k][tx] = in[(size_t)(r0 + ty + k) * cols + (c0 + tx)];
  }
  __syncthreads();
#pragma unroll
  for (int k = 0; k < 32; k += 8) {
    out[(size_t)(c0 + ty + k) * rows + (r0 + tx)] = tile[tx][ty + k];
  }
}

// Forward: one block per batch, 1024 threads. Thread (j = tid&511, h = tid>>9)
// reduces i in [h*256, h*256+256); partials combined via LDS.
__global__ __launch_bounds__(1024, 4) void viterbi_fwd(
    const int* __restrict__ obs,     // [NB][NT]
    const float* __restrict__ start, // [NS]
    const float* __restrict__ trans, // [NS][NS]
    const float* __restrict__ emT,   // [NE][NS]
    float* __restrict__ v)           // [NT][NB][NS]
{
  const int b = blockIdx.x;
  const int tid = threadIdx.x;
  const int j = tid & (NS - 1);
  const int h = tid >> 9;  // 0 or 1 (wave-uniform)

  __shared__ __align__(16) float vcur[NS];
  __shared__ float part[NS];
  __shared__ int obs_s[NT];

  // stage this batch's observation row
  if (tid < NT) obs_s[tid] = obs[b * NT + tid];

  // t = 0 (h==0 half computes)
  if (h == 0) {
    float vj = start[j] + emT[(size_t)obs[b * NT] * NS + j];
    vcur[j] = vj;
    v[((size_t)0 * NB + b) * NS + j] = vj;
  }
  __syncthreads();

  const float* tj = trans + (size_t)(h * 256) * NS + j;  // rows h*256 .. h*256+255
  float e_next = (h == 0) ? emT[(size_t)obs_s[1] * NS + j] : 0.0f;

  for (int t = 1; t < NT; ++t) {
    float e_cur = e_next;
    // prefetch next step's emission early (independent of vcur)
    if (h == 0 && t + 1 < NT) e_next = emT[(size_t)obs_s[t + 1] * NS + j];

    float m0 = -INFINITY, m1 = -INFINITY, m2 = -INFINITY, m3 = -INFINITY;
    const float* vc = vcur + h * 256;
#pragma unroll 8
    for (int i = 0; i < 256; i += 8) {
      float4 va = *reinterpret_cast<const float4*>(vc + i);
      float4 vb = *reinterpret_cast<const float4*>(vc + i + 4);
      float s0 = va.x + tj[(size_t)(i + 0) * NS];
      float s1 = va.y + tj[(size_t)(i + 1) * NS];
      float s2 = va.z + tj[(size_t)(i + 2) * NS];
      float s3 = va.w + tj[(size_t)(i + 3) * NS];
      float s4 = vb.x + tj[(size_t)(i + 4) * NS];
      float s5 = vb.y + tj[(size_t)(i + 5) * NS];
      float s6 = vb.z + tj[(size_t)(i + 6) * NS];
      float s7 = vb.w + tj[(size_t)(i + 7) * NS];
      m0 = fmaxf(m0, fmaxf(s0, s1));  // -> v_max3
      m1 = fmaxf(m1, fmaxf(s2, s3));
      m2 = fmaxf(m2, fmaxf(s4, s5));
      m3 = fmaxf(m3, fmaxf(s6, s7));
    }
    float m = fmaxf(fmaxf(m0, m1), fmaxf(m2, m3));

    if (h == 1) part[j] = m;
    __syncthreads();  // also ensures all vcur reads for this step are done
    if (h == 0) {
      m = fmaxf(m, part[j]);
      float vn = m + e_cur;
      vcur[j] = vn;
      v[((size_t)t * NB + b) * NS + j] = vn;
    }
    __syncthreads();
  }
}

// Backtrace: one wave per batch; recompute argmax with exact first-wins ties.
__global__ __launch_bounds__(64) void viterbi_bt(
    const float* __restrict__ v,      // [NT][NB][NS]
    const float* __restrict__ transT, // [NS][NS], transT[j][i] = trans[i][j]
    int* __restrict__ path)           // [NB][NT] int32
{
  const int b = blockIdx.x;
  const int lane = threadIdx.x;

  // argmax over final v row (first index wins)
  float val = -INFINITY;
  int idx = 0;
  const float* vrow = v + ((size_t)(NT - 1) * NB + b) * NS;
#pragma unroll
  for (int k = 0; k < NS; k += 64) {
    float s = vrow[k + lane];
    if (s > val) { val = s; idx = k + lane; }  // ascending k => strict > keeps first
  }
#pragma unroll
  for (int off = 32; off; off >>= 1) {
    float v2 = __shfl_down(val, off);
    int i2 = __shfl_down(idx, off);
    if (v2 > val || (v2 == val && i2 < idx)) { val = v2; idx = i2; }
  }
  int state = __shfl(idx, 0);
  if (lane == 0) path[b * NT + (NT - 1)] = state;

  for (int t = NT - 1; t >= 1; --t) {
    const float* vp = v + ((size_t)(t - 1) * NB + b) * NS;
    const float* tr = transT + (size_t)state * NS;
    float val2 = -INFINITY;
    int idx2 = 0;
#pragma unroll
    for (int k = 0; k < NS; k += 64) {
      float s = vp[k + lane] + tr[k + lane];
      if (s > val2) { val2 = s; idx2 = k + lane; }
    }
#pragma unroll
    for (int off = 32; off; off >>= 1) {
      float v2 = __shfl_down(val2, off);
      int i2 = __shfl_down(idx2, off);
      if (v2 > val2 || (v2 == val2 && i2 < idx2)) { val2 = v2; idx2 = i2; }
    }
    state = __shfl(idx2, 0);
    if (lane == 0) path[b * NT + (t - 1)] = state;
  }
}

extern "C" void kernel_launch(void* const* d_in, const int* in_sizes, int n_in,
                              void* d_out, int out_size, void* d_ws, size_t ws_size,
                              hipStream_t stream) {
  const int* obs = (const int*)d_in[0];       // [64][512]
  const float* start = (const float*)d_in[1]; // [512]
  const float* trans = (const float*)d_in[2]; // [512][512]
  const float* emis = (const float*)d_in[3];  // [512][2048]
  int* path = (int*)d_out;                    // [64][512] int32

  char* ws = (char*)d_ws;
  float* emT = (float*)ws;                          // [2048][512] = 4 MB
  float* transT = (float*)(ws + (4u << 20));        // [512][512]  = 1 MB
  float* v = (float*)(ws + (5u << 20));             // [512][64][512] = 64 MB

  dim3 tb(32, 8);
  transpose_k<<<dim3(NE / 32, NS / 32), tb, 0, stream>>>(emis, emT, NS, NE);
  transpose_k<<<dim3(NS / 32, NS / 32), tb, 0, stream>>>(trans, transT, NS, NS);
  viterbi_fwd<<<NB, 1024, 0, stream>>>(obs, start, trans, emT, v);
  viterbi_bt<<<NB, 64, 0, stream>>>(v, transT, path);
}